// Round 4
// baseline (38631.870 us; speedup 1.0000x reference)
//
#include <hip/hip_runtime.h>

constexpr int F_ = 36;
constexpr int H_ = 512;
constexpr int B_ = 64;
constexpr int T_ = 1500;
constexpr int C_ = 64;
constexpr int NWG = 256;
constexpr int BLK = 512;
constexpr int NW = BLK / 64;                            // 8 waves

constexpr int FG = 9;                                   // 36/4 f-groups
constexpr size_t BAR_U32 = 256;                         // done[256] epoch flags
constexpr size_t XT_FLOATS = (size_t)T_ * FG * B_ * 4;  // 3,456,000
constexpr int RING_FLOATS = H_ * B_;                    // 32768

#define SCOPE_AGENT __HIP_MEMORY_SCOPE_AGENT

// Write-through (sc0 sc1) stores for cross-WG h state; reads of h are PLAIN
// cached loads made safe by an agent acquire fence (buffer_inv) after the
// epoch poll. Flags: relaxed stores (order provided by the vmcnt(0) drain
// the compiler emits before s_barrier) + relaxed polls.
__device__ __forceinline__ void astore(float* p, float v) {
    __hip_atomic_store(p, v, __ATOMIC_RELAXED, SCOPE_AGENT);
}
__device__ __forceinline__ unsigned aloadu(const unsigned* p) {
    return __hip_atomic_load(p, __ATOMIC_RELAXED, SCOPE_AGENT);
}

__device__ __forceinline__ float sigm(float x) { return 1.0f / (1.0f + __expf(-x)); }
__device__ __forceinline__ float tanhf_(float x) { return 1.0f - 2.0f / (__expf(2.0f * x) + 1.0f); }
__device__ __forceinline__ float dot4(float4 a, float4 b, float acc) {
    return fmaf(a.x, b.x, fmaf(a.y, b.y, fmaf(a.z, b.z, fmaf(a.w, b.w, acc))));
}

// Wave-0 poll: lane b checks flags 4b..4b+3. RMW-free, monotone epochs.
__device__ __forceinline__ void wait_all(const unsigned* done, unsigned tgt, int b) {
    const unsigned* p = done + b * 4;
    for (;;) {
        unsigned d0 = aloadu(p), d1 = aloadu(p + 1), d2 = aloadu(p + 2), d3 = aloadu(p + 3);
        unsigned m = min(min(d0, d1), min(d2, d3));
        if (__all((int)(m >= tgt))) break;
    }
}

__global__ void __launch_bounds__(BLK, 2) lstm_all(
    const float* __restrict__ x,
    const float* __restrict__ Wih0, const float* __restrict__ Whh0,
    const float* __restrict__ bih0, const float* __restrict__ bhh0,
    const float* __restrict__ Wih1, const float* __restrict__ Whh1,
    const float* __restrict__ bih1, const float* __restrict__ bhh1,
    const float* __restrict__ Wout, const float* __restrict__ bout,
    float* __restrict__ out, float* __restrict__ ws, int use_xT)
{
    const int w = blockIdx.x;
    const int tid = threadIdx.x;
    const int v = tid >> 6;      // wave 0..7
    const int b = tid & 63;      // batch lane

    // rows r = g*2 + jj  <->  global gate row g*512 + 2*w + jj  (g: 0=i,1=f,2=g,3=o)
    __shared__ __align__(16) float W0[8][548];     // [r][0..35]=W_ih0, [36..547]=W_hh0
    __shared__ __align__(16) float W1[8][1024];    // [r][0..511]=W_ih1, [512..1023]=W_hh1
    __shared__ float bias0[8], bias1[8];
    __shared__ __align__(16) float part0[NW][8][64];   // [wave][r][b]
    __shared__ __align__(16) float part1[NW][8][64];
    __shared__ float c0[2][64], c2[2][64];             // cell state, WG-private

    unsigned* done = (unsigned*)ws;                    // zeroed by hipMemsetAsync
    float* xT = ws + BAR_U32;
    float* sbase = xT + (use_xT ? XT_FLOATS : 0);
    float* h1r[2] = { sbase, sbase + RING_FLOATS };                       // h1 by t-parity
    float* h2r[2] = { sbase + 2 * RING_FLOATS, sbase + 3 * RING_FLOATS }; // h2 by t-parity

    // ---- init: zero h rings (+ one-time x transpose into [t][f/4][b][4]) ----
    {
        const size_t gstride = (size_t)NWG * BLK;
        const size_t gtid = (size_t)w * BLK + tid;
        for (size_t i = gtid; i < (size_t)4 * RING_FLOATS; i += gstride) astore(&sbase[i], 0.0f);
        if (use_xT) {
            for (size_t i = gtid; i < (size_t)B_ * T_ * F_; i += gstride) {
                int bb = (int)(i / (T_ * F_));
                int rem = (int)(i % (T_ * F_));
                int s = rem / F_, f = rem - s * F_;
                astore(&xT[(size_t)(s * FG + (f >> 2)) * 256 + bb * 4 + (f & 3)], x[i]);
            }
        }
    }
    // ---- one-time weight staging into LDS ----
    for (int idx = tid; idx < 8 * 548; idx += BLK) {
        int r = idx / 548, c = idx - r * 548;
        int grow = (r >> 1) * H_ + 2 * w + (r & 1);
        W0[r][c] = (c < F_) ? Wih0[grow * F_ + c] : Whh0[(size_t)grow * H_ + (c - F_)];
    }
    for (int idx = tid; idx < 8 * 1024; idx += BLK) {
        int r = idx >> 10, c = idx & 1023;
        int grow = (r >> 1) * H_ + 2 * w + (r & 1);
        W1[r][c] = (c < H_) ? Wih1[(size_t)grow * H_ + c] : Whh1[(size_t)grow * H_ + (c - H_)];
    }
    if (tid < 8) {
        int grow = (tid >> 1) * H_ + 2 * w + (tid & 1);
        bias0[tid] = bih0[grow] + bhh0[grow];
        bias1[tid] = bih1[grow] + bhh1[grow];
    }
    if (tid < 128) { c0[tid >> 6][tid & 63] = 0.0f; c2[tid >> 6][tid & 63] = 0.0f; }

    __syncthreads();                      // drains vmcnt(0): init stores at LLC
    if (tid == 0) __hip_atomic_store(&done[w], 1u, __ATOMIC_RELAXED, SCOPE_AGENT);

    const float4* x4g = reinterpret_cast<const float4*>(x);
    const float4* xT4 = reinterpret_cast<const float4*>(xT);

    for (int s = 0; s <= T_; ++s) {
        const float* h1p = h1r[(s + 1) & 1];   // h1[s-1]
        float*       h1c = h1r[s & 1];         // h1[s]
        const float* h2p = h2r[s & 1];         // h2[s-2]
        float*       h2c = h2r[(s + 1) & 1];   // h2[s-1]

        float acc0[8] = {0,0,0,0,0,0,0,0};
        float acc1[8] = {0,0,0,0,0,0,0,0};

        if (s == 0) {                          // xT/h written by other WGs in init
            if (v == 0) wait_all(done, 1u, b);
            __syncthreads();
            __builtin_amdgcn_fence(__ATOMIC_ACQUIRE, "agent");   // inv L1/L2
            __syncthreads();
        }
        // ---- x contribution (layer0, t=s): plain cached, overlaps the poll ----
        if (s < T_) {
            for (int fg = v; fg < FG; fg += NW) {
                float4 xv = use_xT ? xT4[(size_t)(s * FG + fg) * 64 + b]
                                   : x4g[(size_t)b * 13500 + s * FG + fg];
                #pragma unroll
                for (int r = 0; r < 8; ++r)
                    acc0[r] = dot4(xv, *reinterpret_cast<const float4*>(&W0[r][fg << 2]), acc0[r]);
            }
        }
        if (s > 0) {                           // wait for step s-1 everywhere
            if (v == 0) wait_all(done, (unsigned)(s + 1), b);
            __syncthreads();
            __builtin_amdgcn_fence(__ATOMIC_ACQUIRE, "agent");   // inv L1/L2
            __syncthreads();                   // cluster invs before any h load
        }

        // ---- h dots: wave v owns kg in [16v,16v+16). Plain vectorized loads,
        //      staged 16-deep so all 32 dwordx4 issue up front. ----
        {
            const float4* h1p4 = reinterpret_cast<const float4*>(h1p);
            const float4* h2p4 = reinterpret_cast<const float4*>(h2p);
            float4 ha[16], hb[16];
            #pragma unroll
            for (int i = 0; i < 16; ++i) ha[i] = h1p4[(v * 16 + i) * 64 + b];
            #pragma unroll
            for (int i = 0; i < 16; ++i) hb[i] = h2p4[(v * 16 + i) * 64 + b];
            #pragma unroll
            for (int i = 0; i < 16; ++i) {
                int kg = v * 16 + i;
                #pragma unroll
                for (int r = 0; r < 8; ++r)
                    acc0[r] = dot4(ha[i], *reinterpret_cast<const float4*>(&W0[r][F_ + (kg << 2)]), acc0[r]);
                #pragma unroll
                for (int r = 0; r < 8; ++r)
                    acc1[r] = dot4(ha[i], *reinterpret_cast<const float4*>(&W1[r][kg << 2]), acc1[r]);
            }
            #pragma unroll
            for (int i = 0; i < 16; ++i) {
                int kg = v * 16 + i;
                #pragma unroll
                for (int r = 0; r < 8; ++r)
                    acc1[r] = dot4(hb[i], *reinterpret_cast<const float4*>(&W1[r][H_ + (kg << 2)]), acc1[r]);
            }
        }
        #pragma unroll
        for (int r = 0; r < 8; ++r) { part0[v][r][b] = acc0[r]; part1[v][r][b] = acc1[r]; }
        __syncthreads();

        // ---- B: elementwise. waves 0,1 -> layer0 unit 2w+v; waves 2,3 -> layer1. ----
        if (v < 2) {
            if (s < T_) {
                int j = 2 * w + v;
                float pre[4];
                #pragma unroll
                for (int g = 0; g < 4; ++g) {
                    int r = g * 2 + v;
                    float sum = bias0[r];
                    #pragma unroll
                    for (int u = 0; u < NW; ++u) sum += part0[u][r][b];
                    pre[g] = sum;
                }
                float ig = sigm(pre[0]), ff = sigm(pre[1]);
                float gg = tanhf_(pre[2]), og = sigm(pre[3]);
                float c = fmaf(ff, c0[v][b], ig * gg);
                c0[v][b] = c;
                astore(h1c + (j >> 2) * 256 + b * 4 + (j & 3), og * tanhf_(c));
            }
        } else if (v < 4) {
            if (s >= 1) {
                int jj = v - 2, j = 2 * w + jj;
                float pre[4];
                #pragma unroll
                for (int g = 0; g < 4; ++g) {
                    int r = g * 2 + jj;
                    float sum = bias1[r];
                    #pragma unroll
                    for (int u = 0; u < NW; ++u) sum += part1[u][r][b];
                    pre[g] = sum;
                }
                float ig = sigm(pre[0]), ff = sigm(pre[1]);
                float gg = tanhf_(pre[2]), og = sigm(pre[3]);
                float c = fmaf(ff, c2[jj][b], ig * gg);
                c2[jj][b] = c;
                astore(h2c + (j >> 2) * 256 + b * 4 + (j & 3), og * tanhf_(c));
            }
        }
        __syncthreads();                       // vmcnt(0) drain: B stores at LLC
        if (tid == 0)
            __hip_atomic_store(&done[w], (unsigned)(s + 2), __ATOMIC_RELAXED, SCOPE_AGENT);
    }

    // ---- final projection: out = h2[T-1] @ W_out^T + b_out (WGs 0..63, col w) ----
    if (w < C_) {
        if (v == 0) wait_all(done, (unsigned)(T_ + 2), b);
        __syncthreads();
        __builtin_amdgcn_fence(__ATOMIC_ACQUIRE, "agent");
        __syncthreads();
        const float4* h2l = reinterpret_cast<const float4*>(h2r[(T_ - 1) & 1]);
        const float4* wo = reinterpret_cast<const float4*>(Wout) + (size_t)w * 128;
        float a = 0.0f;
        #pragma unroll
        for (int kg = v * 16; kg < v * 16 + 16; ++kg)
            a = dot4(h2l[kg * 64 + b], wo[kg], a);
        part0[v][0][b] = a;
        __syncthreads();
        if (v == 0) {
            float sum = bout[w];
            #pragma unroll
            for (int u = 0; u < NW; ++u) sum += part0[u][0][b];
            out[b * C_ + w] = sum;
        }
    }
}

extern "C" void kernel_launch(void* const* d_in, const int* in_sizes, int n_in,
                              void* d_out, int out_size, void* d_ws, size_t ws_size,
                              hipStream_t stream)
{
    const float* x    = (const float*)d_in[0];
    const float* Wih0 = (const float*)d_in[1];
    const float* Whh0 = (const float*)d_in[2];
    const float* bih0 = (const float*)d_in[3];
    const float* bhh0 = (const float*)d_in[4];
    const float* Wih1 = (const float*)d_in[5];
    const float* Whh1 = (const float*)d_in[6];
    const float* bih1 = (const float*)d_in[7];
    const float* bhh1 = (const float*)d_in[8];
    const float* Wout = (const float*)d_in[9];
    const float* bout = (const float*)d_in[10];
    float* out = (float*)d_out;
    float* ws  = (float*)d_ws;

    size_t need = (BAR_U32 + XT_FLOATS + 4ull * RING_FLOATS) * sizeof(float);
    int use_xT = (ws_size >= need) ? 1 : 0;

    // reset epoch flags (deterministic across graph replays)
    hipMemsetAsync(d_ws, 0, BAR_U32 * sizeof(unsigned), stream);

    void* args[] = { (void*)&x, (void*)&Wih0, (void*)&Whh0, (void*)&bih0, (void*)&bhh0,
                     (void*)&Wih1, (void*)&Whh1, (void*)&bih1, (void*)&bhh1,
                     (void*)&Wout, (void*)&bout, (void*)&out, (void*)&ws, (void*)&use_xT };
    hipLaunchCooperativeKernel((void*)lstm_all, dim3(NWG), dim3(BLK), args, 0, stream);
}

// Round 5
// 21179.915 us; speedup vs baseline: 1.8240x; 1.8240x over previous
//
#include <hip/hip_runtime.h>

constexpr int F_ = 36;
constexpr int H_ = 512;
constexpr int B_ = 64;
constexpr int T_ = 1500;
constexpr int C_ = 64;
constexpr int NWG = 256;
constexpr int BLK = 512;
constexpr int NW = BLK / 64;                            // 8 waves

constexpr int FG = 9;                                   // 36/4 f-groups
constexpr size_t BAR_U32 = 256;                         // done[256] epoch flags
constexpr size_t XT_FLOATS = (size_t)T_ * FG * B_ * 4;  // 3,456,000
constexpr int RING_FLOATS = H_ * B_;                    // 32768

#define SCOPE_AGENT __HIP_MEMORY_SCOPE_AGENT

// Producers: write-through stores (sc0 sc1) -> data at LLC when drained.
__device__ __forceinline__ void astore(float* p, float v) {
    __hip_atomic_store(p, v, __ATOMIC_RELAXED, SCOPE_AGENT);
}

// Consumers: single 16B LLC load (sc0 sc1). Atomic float loads can't
// vectorize, so emit the dwordx4 directly. asm volatile keeps issue order;
// completion is claimed by the counted s_waitcnt below.
__device__ __forceinline__ float4 llc_load4(const float* p) {
    float4 r;
    asm volatile("global_load_dwordx4 %0, %1, off sc0 sc1" : "=v"(r) : "v"(p));
    return r;
}
__device__ __forceinline__ uint4 llc_load4u(const unsigned* p) {
    uint4 r;
    asm volatile("global_load_dwordx4 %0, %1, off sc0 sc1" : "=v"(r) : "v"(p));
    return r;
}
// rule #18: sched_barrier(0) right after an inline-asm waitcnt, else hipcc
// hoists register-only consumers above it.
__device__ __forceinline__ void vm_wait(int n) {
    if (n == 0)       asm volatile("s_waitcnt vmcnt(0)" ::: "memory");
    else if (n == 16) asm volatile("s_waitcnt vmcnt(16)" ::: "memory");
    __builtin_amdgcn_sched_barrier(0);
}

__device__ __forceinline__ float sigm(float x) { return 1.0f / (1.0f + __expf(-x)); }
__device__ __forceinline__ float tanhf_(float x) { return 1.0f - 2.0f / (__expf(2.0f * x) + 1.0f); }
__device__ __forceinline__ float dot4(float4 a, float4 b, float acc) {
    return fmaf(a.x, b.x, fmaf(a.y, b.y, fmaf(a.z, b.z, fmaf(a.w, b.w, acc))));
}

// All-wave poll: lane b checks flags 4b..4b+3 as one 16B LLC load.
// RMW-free, monotone epochs; every wave exits independently.
__device__ __forceinline__ void wait_all(const unsigned* done, unsigned tgt, int b) {
    const unsigned* p = done + (b << 2);
    for (;;) {
        uint4 d = llc_load4u(p);
        vm_wait(0);
        unsigned m = min(min(d.x, d.y), min(d.z, d.w));
        if (__all((int)(m >= tgt))) break;
    }
}

__global__ void __launch_bounds__(BLK, 2) lstm_all(
    const float* __restrict__ x,
    const float* __restrict__ Wih0, const float* __restrict__ Whh0,
    const float* __restrict__ bih0, const float* __restrict__ bhh0,
    const float* __restrict__ Wih1, const float* __restrict__ Whh1,
    const float* __restrict__ bih1, const float* __restrict__ bhh1,
    const float* __restrict__ Wout, const float* __restrict__ bout,
    float* __restrict__ out, float* __restrict__ ws, int use_xT)
{
    const int w = blockIdx.x;
    const int tid = threadIdx.x;
    const int v = tid >> 6;      // wave 0..7
    const int b = tid & 63;      // batch lane

    // rows r = g*2 + jj  <->  global gate row g*512 + 2*w + jj  (g: 0=i,1=f,2=g,3=o)
    __shared__ __align__(16) float W0[8][548];     // [r][0..35]=W_ih0, [36..547]=W_hh0
    __shared__ __align__(16) float W1[8][1024];    // [r][0..511]=W_ih1, [512..1023]=W_hh1
    __shared__ float bias0[8], bias1[8];
    __shared__ __align__(16) float part0[NW][8][64];   // [wave][r][b]
    __shared__ __align__(16) float part1[NW][8][64];
    __shared__ float c0[2][64], c2[2][64];             // cell state, WG-private

    unsigned* done = (unsigned*)ws;                    // zeroed by hipMemsetAsync
    float* xT = ws + BAR_U32;
    float* sbase = xT + (use_xT ? XT_FLOATS : 0);
    float* h1r[2] = { sbase, sbase + RING_FLOATS };                       // h1 by t-parity
    float* h2r[2] = { sbase + 2 * RING_FLOATS, sbase + 3 * RING_FLOATS }; // h2 by t-parity

    // ---- init: zero h rings (+ one-time x transpose into [t][f/4][b][4]) ----
    {
        const size_t gstride = (size_t)NWG * BLK;
        const size_t gtid = (size_t)w * BLK + tid;
        for (size_t i = gtid; i < (size_t)4 * RING_FLOATS; i += gstride) astore(&sbase[i], 0.0f);
        if (use_xT) {
            for (size_t i = gtid; i < (size_t)B_ * T_ * F_; i += gstride) {
                int bb = (int)(i / (T_ * F_));
                int rem = (int)(i % (T_ * F_));
                int s = rem / F_, f = rem - s * F_;
                astore(&xT[(size_t)(s * FG + (f >> 2)) * 256 + bb * 4 + (f & 3)], x[i]);
            }
        }
    }
    // ---- one-time weight staging into LDS ----
    for (int idx = tid; idx < 8 * 548; idx += BLK) {
        int r = idx / 548, c = idx - r * 548;
        int grow = (r >> 1) * H_ + 2 * w + (r & 1);
        W0[r][c] = (c < F_) ? Wih0[grow * F_ + c] : Whh0[(size_t)grow * H_ + (c - F_)];
    }
    for (int idx = tid; idx < 8 * 1024; idx += BLK) {
        int r = idx >> 10, c = idx & 1023;
        int grow = (r >> 1) * H_ + 2 * w + (r & 1);
        W1[r][c] = (c < H_) ? Wih1[(size_t)grow * H_ + c] : Whh1[(size_t)grow * H_ + (c - H_)];
    }
    if (tid < 8) {
        int grow = (tid >> 1) * H_ + 2 * w + (tid & 1);
        bias0[tid] = bih0[grow] + bhh0[grow];
        bias1[tid] = bih1[grow] + bhh1[grow];
    }
    if (tid < 128) { c0[tid >> 6][tid & 63] = 0.0f; c2[tid >> 6][tid & 63] = 0.0f; }

    __syncthreads();                      // drains vmcnt(0): init stores at LLC
    if (tid == 0) __hip_atomic_store(&done[w], 1u, __ATOMIC_RELAXED, SCOPE_AGENT);

    const float4* x4g = reinterpret_cast<const float4*>(x);
    const float4* xT4 = reinterpret_cast<const float4*>(xT);   // immutable after init

    for (int s = 0; s <= T_; ++s) {
        const float* h1p = h1r[(s + 1) & 1];   // h1[s-1]
        float*       h1c = h1r[s & 1];         // h1[s]
        const float* h2p = h2r[s & 1];         // h2[s-2]
        float*       h2c = h2r[(s + 1) & 1];   // h2[s-1]

        float acc0[8] = {0,0,0,0,0,0,0,0};
        float acc1[8] = {0,0,0,0,0,0,0,0};

        if (s == 0) wait_all(done, 1u, b);     // xT/h rings written by all WGs

        // ---- x contribution (layer0, t=s): plain cached loads ----
        if (s < T_) {
            for (int fg = v; fg < FG; fg += NW) {
                float4 xv = use_xT ? xT4[(size_t)(s * FG + fg) * 64 + b]
                                   : x4g[(size_t)b * 13500 + s * FG + fg];
                #pragma unroll
                for (int r = 0; r < 8; ++r)
                    acc0[r] = dot4(xv, *reinterpret_cast<const float4*>(&W0[r][fg << 2]), acc0[r]);
            }
        }

        if (s > 0) wait_all(done, (unsigned)(s + 1), b);   // step s-1 done everywhere

        // ---- issue all 32 LLC loads (16 h1 + 16 h2), then counted waits ----
        __builtin_amdgcn_sched_barrier(0);     // keep x-part code above the batch
        const float* base1 = h1p + (v * 16) * 256 + (b << 2);
        const float* base2 = h2p + (v * 16) * 256 + (b << 2);
        float4 ha[16], hb[16];
        #pragma unroll
        for (int i = 0; i < 16; ++i) ha[i] = llc_load4(base1 + i * 256);
        #pragma unroll
        for (int i = 0; i < 16; ++i) hb[i] = llc_load4(base2 + i * 256);

        vm_wait(16);                           // ha complete (FIFO), hb in flight
        #pragma unroll
        for (int i = 0; i < 16; ++i) {
            int kg = v * 16 + i;
            #pragma unroll
            for (int r = 0; r < 8; ++r)
                acc0[r] = dot4(ha[i], *reinterpret_cast<const float4*>(&W0[r][F_ + (kg << 2)]), acc0[r]);
            #pragma unroll
            for (int r = 0; r < 8; ++r)
                acc1[r] = dot4(ha[i], *reinterpret_cast<const float4*>(&W1[r][kg << 2]), acc1[r]);
        }
        vm_wait(0);                            // hb complete
        #pragma unroll
        for (int i = 0; i < 16; ++i) {
            int kg = v * 16 + i;
            #pragma unroll
            for (int r = 0; r < 8; ++r)
                acc1[r] = dot4(hb[i], *reinterpret_cast<const float4*>(&W1[r][H_ + (kg << 2)]), acc1[r]);
        }
        #pragma unroll
        for (int r = 0; r < 8; ++r) { part0[v][r][b] = acc0[r]; part1[v][r][b] = acc1[r]; }
        __syncthreads();

        // ---- B: elementwise. waves 0,1 -> layer0 unit 2w+v; waves 2,3 -> layer1. ----
        if (v < 2) {
            if (s < T_) {
                int j = 2 * w + v;
                float pre[4];
                #pragma unroll
                for (int g = 0; g < 4; ++g) {
                    int r = g * 2 + v;
                    float sum = bias0[r];
                    #pragma unroll
                    for (int u = 0; u < NW; ++u) sum += part0[u][r][b];
                    pre[g] = sum;
                }
                float ig = sigm(pre[0]), ff = sigm(pre[1]);
                float gg = tanhf_(pre[2]), og = sigm(pre[3]);
                float c = fmaf(ff, c0[v][b], ig * gg);
                c0[v][b] = c;
                astore(h1c + (j >> 2) * 256 + b * 4 + (j & 3), og * tanhf_(c));
            }
        } else if (v < 4) {
            if (s >= 1) {
                int jj = v - 2, j = 2 * w + jj;
                float pre[4];
                #pragma unroll
                for (int g = 0; g < 4; ++g) {
                    int r = g * 2 + jj;
                    float sum = bias1[r];
                    #pragma unroll
                    for (int u = 0; u < NW; ++u) sum += part1[u][r][b];
                    pre[g] = sum;
                }
                float ig = sigm(pre[0]), ff = sigm(pre[1]);
                float gg = tanhf_(pre[2]), og = sigm(pre[3]);
                float c = fmaf(ff, c2[jj][b], ig * gg);
                c2[jj][b] = c;
                astore(h2c + (j >> 2) * 256 + b * 4 + (j & 3), og * tanhf_(c));
            }
        }
        __syncthreads();                       // vmcnt(0) drain: B stores at LLC
        if (tid == 0)
            __hip_atomic_store(&done[w], (unsigned)(s + 2), __ATOMIC_RELAXED, SCOPE_AGENT);
    }

    // ---- final projection: out = h2[T-1] @ W_out^T + b_out (WGs 0..63, col w) ----
    if (w < C_) {
        wait_all(done, (unsigned)(T_ + 2), b);
        const float* h2l = h2r[(T_ - 1) & 1];
        const float4* wo = reinterpret_cast<const float4*>(Wout) + (size_t)w * 128;
        const float* basep = h2l + (v * 16) * 256 + (b << 2);
        float4 hv[16];
        #pragma unroll
        for (int i = 0; i < 16; ++i) hv[i] = llc_load4(basep + i * 256);
        vm_wait(0);
        float a = 0.0f;
        #pragma unroll
        for (int i = 0; i < 16; ++i)
            a = dot4(hv[i], wo[v * 16 + i], a);
        part0[v][0][b] = a;
        __syncthreads();
        if (v == 0) {
            float sum = bout[w];
            #pragma unroll
            for (int u = 0; u < NW; ++u) sum += part0[u][0][b];
            out[b * C_ + w] = sum;
        }
    }
}

extern "C" void kernel_launch(void* const* d_in, const int* in_sizes, int n_in,
                              void* d_out, int out_size, void* d_ws, size_t ws_size,
                              hipStream_t stream)
{
    const float* x    = (const float*)d_in[0];
    const float* Wih0 = (const float*)d_in[1];
    const float* Whh0 = (const float*)d_in[2];
    const float* bih0 = (const float*)d_in[3];
    const float* bhh0 = (const float*)d_in[4];
    const float* Wih1 = (const float*)d_in[5];
    const float* Whh1 = (const float*)d_in[6];
    const float* bih1 = (const float*)d_in[7];
    const float* bhh1 = (const float*)d_in[8];
    const float* Wout = (const float*)d_in[9];
    const float* bout = (const float*)d_in[10];
    float* out = (float*)d_out;
    float* ws  = (float*)d_ws;

    size_t need = (BAR_U32 + XT_FLOATS + 4ull * RING_FLOATS) * sizeof(float);
    int use_xT = (ws_size >= need) ? 1 : 0;

    // reset epoch flags (in-graph, deterministic across replays)
    hipMemsetAsync(d_ws, 0, BAR_U32 * sizeof(unsigned), stream);

    void* args[] = { (void*)&x, (void*)&Wih0, (void*)&Whh0, (void*)&bih0, (void*)&bhh0,
                     (void*)&Wih1, (void*)&Whh1, (void*)&bih1, (void*)&bhh1,
                     (void*)&Wout, (void*)&bout, (void*)&out, (void*)&ws, (void*)&use_xT };
    hipLaunchCooperativeKernel((void*)lstm_all, dim3(NWG), dim3(BLK), args, 0, stream);
}